// Round 11
// baseline (389.782 us; speedup 1.0000x reference)
//
#include <hip/hip_runtime.h>

// Problem constants (match reference)
constexpr int K    = 27;
constexpr int CIN  = 16;
constexpr int COUT = 4;
constexpr int NS   = 3;
constexpr int WSZ  = K * CIN * COUT;   // 1728 floats per stencil
constexpr int WPAD = WSZ + 8;          // pad for fallback kernel

// Lane-owned chunk-sorted gather configuration
constexpr int NCH  = 64;               // sort chunks: 16K rows = 512KB f16 windows
constexpr int CHSH = 14;               // chunk = nb >> 14 (requires n <= 2^20)
constexpr int NPL  = 2;                // particles per lane
constexpr int NPW  = 128;              // particles per wave
constexpr int RNDS = K * NPL;          // 54 fixed rounds per lane column
constexpr int EPW  = RNDS * 64;        // 3456 entries per wave (column layout)
constexpr unsigned int SENT = 0xFFFFFFFFu;
constexpr int WREG = 34;               // W region stride (dwords), f16 pairs

typedef unsigned int uint;
typedef float  f32x4 __attribute__((ext_vector_type(4)));
typedef uint   u32x4 __attribute__((ext_vector_type(4)));
typedef uint   u32x2 __attribute__((ext_vector_type(2)));
typedef _Float16 h16x2 __attribute__((ext_vector_type(2)));

__device__ __forceinline__ uint pkh(float lo, float hi) {
    union { h16x2 h; uint u; } v;
    v.h.x = (_Float16)lo; v.h.y = (_Float16)hi;   // RNE casts
    return v.u;
}
__device__ __forceinline__ h16x2 u2h(uint u) {
    union { uint u; h16x2 h; } v; v.u = u; return v.h;
}

#if defined(__has_builtin)
#if __has_builtin(__builtin_amdgcn_fdot2)
#define HAVE_FDOT2 1
#endif
#endif

__device__ __forceinline__ float dot2acc(uint xp, uint wp, float acc) {
#ifdef HAVE_FDOT2
    return __builtin_amdgcn_fdot2(u2h(xp), u2h(wp), acc, false);
#else
    const h16x2 a = u2h(xp), b = u2h(wp);
    acc = fmaf((float)a.x, (float)b.x, acc);
    return fmaf((float)a.y, (float)b.y, acc);
#endif
}

// bf16 helpers (fallback path only)
__device__ __forceinline__ uint bf16_rne(float f) {
    uint u = __float_as_uint(f);
    u += 0x7FFFu + ((u >> 16) & 1u);
    return u >> 16;
}
__device__ __forceinline__ float blo(uint u) { return __uint_as_float(u << 16); }
__device__ __forceinline__ float bhi(uint u) { return __uint_as_float(u & 0xFFFF0000u); }

// ---- pass 1: x fp32 -> f16 (RNE), packed 2 per dword ----
__global__ __launch_bounds__(256) void cvt_f16(
    const float* __restrict__ x, uint* __restrict__ xh, int nvec)
{
    int i = blockIdx.x * 256 + threadIdx.x;
    if (i >= nvec) return;                 // nvec = N*CIN/8
    const f32x4* xf = reinterpret_cast<const f32x4*>(x) + 2 * (size_t)i;
    f32x4 a = __builtin_nontemporal_load(&xf[0]);
    f32x4 b = __builtin_nontemporal_load(&xf[1]);
    u32x4 o;
    o.x = pkh(a.x, a.y);
    o.y = pkh(a.z, a.w);
    o.z = pkh(b.x, b.y);
    o.w = pkh(b.z, b.w);
    __builtin_nontemporal_store(o, &reinterpret_cast<u32x4*>(xh)[i]);
}

// ---- pass 2: per-LANE counting sort of own 54 taps by x-chunk ----
// Entry: nb(20)<<9 | b(2)<<7 | s(2)<<5 | j(5). Column layout ent[slot*64+lane].
// All LDS cells lane-column-private (bank = lane mod 32, 2-way free).
__global__ __launch_bounds__(64) void bucket_kernel(
    const int* __restrict__ aprs,    // [n, 27]
    const int* __restrict__ lvl,     // [n]
    uint* __restrict__ ent,          // [nwaves, EPW]
    int n)
{
    __shared__ uint stage[EPW];          // 13.8 KB
    __shared__ int  posL[NCH * 64];      // 16 KB cursors

    const int w    = blockIdx.x;
    const int lane = threadIdx.x;
    const int i0   = w * NPW + lane * NPL;
    const int* __restrict__ ap = aprs + (size_t)i0 * K;

    #pragma unroll
    for (int c = 0; c < NCH; ++c) posL[c * 64 + lane] = 0;
    for (int t = 0; t < RNDS; ++t) stage[t * 64 + lane] = SENT;

    // histogram of this lane's taps
    for (int b = 0; b < NPL; ++b) {
        if (i0 + b < n) {
            for (int j = 0; j < K; ++j) {
                const int ch = (int)(((uint)ap[b * K + j]) >> CHSH);
                posL[ch * 64 + lane] += 1;
            }
        }
    }
    // per-lane exclusive prefix (serial over 64 cells)
    int run = 0;
    #pragma unroll
    for (int c = 0; c < NCH; ++c) {
        const int cc = posL[c * 64 + lane];
        posL[c * 64 + lane] = run;
        run += cc;
    }
    // emit chunk-sorted entries into own column (aprs re-read hits L1/L2)
    for (int b = 0; b < NPL; ++b) {
        if (i0 + b < n) {
            const uint s = (uint)lvl[i0 + b];
            const uint tag = ((uint)b << 7) | (s << 5);
            for (int j = 0; j < K; ++j) {
                const uint nb = (uint)ap[b * K + j];
                const int ch  = (int)(nb >> CHSH);
                const int slot = posL[ch * 64 + lane];
                posL[ch * 64 + lane] = slot + 1;
                stage[slot * 64 + lane] = (nb << 9) | tag | (uint)j;
            }
        }
    }
    // dump own column (coalesced across lanes)
    uint* __restrict__ eb = ent + (size_t)w * EPW;
    for (int t = 0; t < RNDS; ++t) eb[t * 64 + lane] = stage[t * 64 + lane];
}

// ---- pass 3: free-running fixed-54-round gather, f16 dot2, register acc ----
// 8192 waves = 2048 blocks = 8 blocks/CU -> 32 waves/CU occupancy ceiling.
__global__ __launch_bounds__(256, 8) void compute_kernel(
    const uint*  __restrict__ xh,    // [n, 8] dwords (16 f16)
    const float* __restrict__ Wg,    // [3, 27, 16, 4] f32
    const uint*  __restrict__ ent,   // [nwaves, EPW]
    float*       __restrict__ out,   // [n, 4]
    int n)
{
    // W repacked for dot2: region sk -> dword (q*8+p) = f16 pair (W[2p][q], W[2p+1][q])
    __shared__ __align__(8) uint Wb[NS * K * WREG];   // 81 * 34 dwords = 11 KB

    const int tid = threadIdx.x;
    for (int idx = tid; idx < NS * K * 32; idx += 256) {
        const int reg = idx >> 5, g = idx & 31;
        const int q = g >> 3, p = g & 7;
        Wb[reg * WREG + g] = pkh(Wg[reg * 64 + 8 * p + q],
                                 Wg[reg * 64 + 8 * p + 4 + q]);
    }
    __syncthreads();

    const int widx = tid >> 6, lane = tid & 63;
    const int w = blockIdx.x * 4 + widx;
    const uint* __restrict__ eb = ent + (size_t)w * EPW;

    f32x4 A0 = {0,0,0,0}, A1 = {0,0,0,0};

    // prime 3-deep pipeline: entries s,s+1,s+2; x for s and s+1 in flight
    uint eC  = eb[lane];
    uint eN  = eb[64 + lane];
    uint eN2 = eb[128 + lane];
    {
        const uint nbC = (eC == SENT) ? 0u : (eC >> 9);
        const u32x4* __restrict__ xrC =
            reinterpret_cast<const u32x4*>(xh + (size_t)nbC * 8);
        u32x4 xC0 = xrC[0];
        u32x4 xC1 = xrC[1];
        const uint nbN = (eN == SENT) ? 0u : (eN >> 9);
        const u32x4* __restrict__ xrN =
            reinterpret_cast<const u32x4*>(xh + (size_t)nbN * 8);
        u32x4 xN0 = xrN[0];
        u32x4 xN1 = xrN[1];

        for (int s = 0; s < RNDS; ++s) {
            // (1) entry prefetch for slot s+3
            const int sF = (s + 3 < RNDS) ? s + 3 : RNDS - 1;
            const uint eF = eb[(size_t)sF * 64 + lane];
            // (2) x prefetch for slot s+2
            const uint nb2 = (eN2 == SENT) ? 0u : (eN2 >> 9);
            const u32x4* __restrict__ xr2 =
                reinterpret_cast<const u32x4*>(xh + (size_t)nb2 * 8);
            const u32x4 x20 = xr2[0];
            const u32x4 x21 = xr2[1];

            // (3) compute slot s
            const bool valid = (eC != SENT);
            const uint bq  = (eC >> 7) & 3u;
            const uint skr = ((eC >> 5) & 3u) * (uint)K + (eC & 31u);
            const uint sk  = valid ? skr : 0u;
            const uint* __restrict__ wr = &Wb[sk * WREG];

            uint xd[8];
            xd[0] = xC0.x; xd[1] = xC0.y; xd[2] = xC0.z; xd[3] = xC0.w;
            xd[4] = xC1.x; xd[5] = xC1.y; xd[6] = xC1.z; xd[7] = xC1.w;

            float pq0 = 0.f, pq1 = 0.f, pq2 = 0.f, pq3 = 0.f;
            #pragma unroll
            for (int t = 0; t < 4; ++t) {
                const u32x2 w0 = *reinterpret_cast<const u32x2*>(wr +  0 + 2 * t);
                const u32x2 w1 = *reinterpret_cast<const u32x2*>(wr +  8 + 2 * t);
                const u32x2 w2 = *reinterpret_cast<const u32x2*>(wr + 16 + 2 * t);
                const u32x2 w3 = *reinterpret_cast<const u32x2*>(wr + 24 + 2 * t);
                pq0 = dot2acc(xd[2 * t], w0.x, pq0);
                pq0 = dot2acc(xd[2 * t + 1], w0.y, pq0);
                pq1 = dot2acc(xd[2 * t], w1.x, pq1);
                pq1 = dot2acc(xd[2 * t + 1], w1.y, pq1);
                pq2 = dot2acc(xd[2 * t], w2.x, pq2);
                pq2 = dot2acc(xd[2 * t + 1], w2.y, pq2);
                pq3 = dot2acc(xd[2 * t], w3.x, pq3);
                pq3 = dot2acc(xd[2 * t + 1], w3.y, pq3);
            }
            const float m0 = (valid && bq == 0u) ? 1.f : 0.f;
            const float m1 = (valid && bq == 1u) ? 1.f : 0.f;
            A0.x = fmaf(m0, pq0, A0.x); A0.y = fmaf(m0, pq1, A0.y);
            A0.z = fmaf(m0, pq2, A0.z); A0.w = fmaf(m0, pq3, A0.w);
            A1.x = fmaf(m1, pq0, A1.x); A1.y = fmaf(m1, pq1, A1.y);
            A1.z = fmaf(m1, pq2, A1.z); A1.w = fmaf(m1, pq3, A1.w);

            // rotate 3-deep pipeline
            eC = eN;  xC0 = xN0; xC1 = xN1;
            eN = eN2; xN0 = x20; xN1 = x21;
            eN2 = eF;
        }
    }

    // epilogue: relu + per-lane 32B contiguous stores
    const int i0 = w * NPW + lane * NPL;
    f32x4* __restrict__ op = reinterpret_cast<f32x4*>(out);
    f32x4 o;
    if (i0 + 0 < n) {
        o.x = fmaxf(A0.x,0.f); o.y = fmaxf(A0.y,0.f); o.z = fmaxf(A0.z,0.f); o.w = fmaxf(A0.w,0.f);
        __builtin_nontemporal_store(o, op + i0 + 0);
    }
    if (i0 + 1 < n) {
        o.x = fmaxf(A1.x,0.f); o.y = fmaxf(A1.y,0.f); o.z = fmaxf(A1.z,0.f); o.w = fmaxf(A1.w,0.f);
        __builtin_nontemporal_store(o, op + i0 + 1);
    }
}

// ---- fallback chain (bf16 flat gather, r4-proven) ----
__global__ __launch_bounds__(256) void cvt_bf16(
    const float* __restrict__ x, uint* __restrict__ xh, int nvec)
{
    int i = blockIdx.x * 256 + threadIdx.x;
    if (i >= nvec) return;
    const f32x4* xf = reinterpret_cast<const f32x4*>(x) + 2 * (size_t)i;
    f32x4 a = __builtin_nontemporal_load(&xf[0]);
    f32x4 b = __builtin_nontemporal_load(&xf[1]);
    u32x4 o;
    o.x = bf16_rne(a.x) | (bf16_rne(a.y) << 16);
    o.y = bf16_rne(a.z) | (bf16_rne(a.w) << 16);
    o.z = bf16_rne(b.x) | (bf16_rne(b.y) << 16);
    o.w = bf16_rne(b.z) | (bf16_rne(b.w) << 16);
    __builtin_nontemporal_store(o, &reinterpret_cast<u32x4*>(xh)[i]);
}

__global__ __launch_bounds__(256) void outblock_bf16(
    const uint*  __restrict__ xh,
    const float* __restrict__ W,
    const int*   __restrict__ aprs,
    const int*   __restrict__ lvl,
    float*       __restrict__ out,
    int n)
{
    __shared__ float Wl[NS * WPAD];
    for (int i = threadIdx.x; i < NS * WSZ; i += 256) {
        int s = i / WSZ;
        Wl[s * WPAD + (i - s * WSZ)] = W[i];
    }
    __syncthreads();

    int nIdx = blockIdx.x * 256 + threadIdx.x;
    if (nIdx >= n) return;

    const int s = lvl[nIdx];
    const float* __restrict__ Ws = &Wl[s * WPAD];
    const int*   __restrict__ ap = aprs + (size_t)nIdx * K;

    float a0 = 0.f, a1 = 0.f, a2 = 0.f, a3 = 0.f;
    #pragma unroll 3
    for (int k = 0; k < K; ++k) {
        const int nb = ap[k];
        const u32x4* __restrict__ xr =
            reinterpret_cast<const u32x4*>(xh + (size_t)nb * 8);
        const u32x4 p0 = xr[0];
        const u32x4 p1 = xr[1];
        const float* __restrict__ Wk = Ws + k * (CIN * COUT);
        float xv[16];
        xv[ 0] = blo(p0.x); xv[ 1] = bhi(p0.x);
        xv[ 2] = blo(p0.y); xv[ 3] = bhi(p0.y);
        xv[ 4] = blo(p0.z); xv[ 5] = bhi(p0.z);
        xv[ 6] = blo(p0.w); xv[ 7] = bhi(p0.w);
        xv[ 8] = blo(p1.x); xv[ 9] = bhi(p1.x);
        xv[10] = blo(p1.y); xv[11] = bhi(p1.y);
        xv[12] = blo(p1.z); xv[13] = bhi(p1.z);
        xv[14] = blo(p1.w); xv[15] = bhi(p1.w);
        #pragma unroll
        for (int cq = 0; cq < CIN; ++cq) {
            const float4 wv = *reinterpret_cast<const float4*>(&Wk[cq * COUT]);
            a0 = fmaf(xv[cq], wv.x, a0);
            a1 = fmaf(xv[cq], wv.y, a1);
            a2 = fmaf(xv[cq], wv.z, a2);
            a3 = fmaf(xv[cq], wv.w, a3);
        }
    }
    f32x4 o;
    o.x = fmaxf(a0, 0.f); o.y = fmaxf(a1, 0.f);
    o.z = fmaxf(a2, 0.f); o.w = fmaxf(a3, 0.f);
    __builtin_nontemporal_store(o, reinterpret_cast<f32x4*>(out) + nIdx);
}

__global__ __launch_bounds__(256) void outblock_f32(
    const float* __restrict__ x,
    const float* __restrict__ W,
    const int*   __restrict__ aprs,
    const int*   __restrict__ lvl,
    float*       __restrict__ out,
    int n)
{
    __shared__ float Wl[NS * WPAD];
    for (int i = threadIdx.x; i < NS * WSZ; i += 256) {
        int s = i / WSZ;
        Wl[s * WPAD + (i - s * WSZ)] = W[i];
    }
    __syncthreads();
    int nIdx = blockIdx.x * 256 + threadIdx.x;
    if (nIdx >= n) return;
    const int s = lvl[nIdx];
    const float* __restrict__ Ws = &Wl[s * WPAD];
    const int*   __restrict__ ap = aprs + (size_t)nIdx * K;
    float a0 = 0.f, a1 = 0.f, a2 = 0.f, a3 = 0.f;
    #pragma unroll 3
    for (int k = 0; k < K; ++k) {
        const int nb = ap[k];
        const float4* __restrict__ xr =
            reinterpret_cast<const float4*>(x + (size_t)nb * CIN);
        const float4 v0 = xr[0], v1 = xr[1], v2 = xr[2], v3 = xr[3];
        const float* __restrict__ Wk = Ws + k * (CIN * COUT);
        float xv[16];
        xv[ 0] = v0.x; xv[ 1] = v0.y; xv[ 2] = v0.z; xv[ 3] = v0.w;
        xv[ 4] = v1.x; xv[ 5] = v1.y; xv[ 6] = v1.z; xv[ 7] = v1.w;
        xv[ 8] = v2.x; xv[ 9] = v2.y; xv[10] = v2.z; xv[11] = v2.w;
        xv[12] = v3.x; xv[13] = v3.y; xv[14] = v3.z; xv[15] = v3.w;
        #pragma unroll
        for (int cq = 0; cq < CIN; ++cq) {
            const float4 wv = *reinterpret_cast<const float4*>(&Wk[cq * COUT]);
            a0 = fmaf(xv[cq], wv.x, a0);
            a1 = fmaf(xv[cq], wv.y, a1);
            a2 = fmaf(xv[cq], wv.z, a2);
            a3 = fmaf(xv[cq], wv.w, a3);
        }
    }
    float4 o;
    o.x = fmaxf(a0, 0.f); o.y = fmaxf(a1, 0.f);
    o.z = fmaxf(a2, 0.f); o.w = fmaxf(a3, 0.f);
    reinterpret_cast<float4*>(out)[nIdx] = o;
}

extern "C" void kernel_launch(void* const* d_in, const int* in_sizes, int n_in,
                              void* d_out, int out_size, void* d_ws, size_t ws_size,
                              hipStream_t stream) {
    const float* x    = (const float*)d_in[0];
    const float* W    = (const float*)d_in[1];
    const int*   aprs = (const int*)d_in[2];
    const int*   lvl  = (const int*)d_in[3];
    float*       out  = (float*)d_out;

    const int n = in_sizes[0] / CIN;               // N particles

    const int nwaves    = (n + NPW - 1) / NPW;
    const int nblocks   = (nwaves + 3) / 4;        // 4 waves per compute block
    const int nwavesPad = nblocks * 4;

    const size_t xhB  = (size_t)n * CIN * 2;             // 32 MB f16 x copy
    const size_t entB = (size_t)nwavesPad * EPW * 4;     // ~113 MB entries
    const size_t needChunked = xhB + entB;

    if (ws_size >= needChunked && n <= (1 << 20)) {
        uint* xh  = (uint*)d_ws;
        uint* ent = (uint*)((char*)d_ws + xhB);
        const int nvec = n * CIN / 8;
        cvt_f16<<<(nvec + 255) / 256, 256, 0, stream>>>(x, xh, nvec);
        bucket_kernel<<<nwavesPad, 64, 0, stream>>>(aprs, lvl, ent, n);
        compute_kernel<<<nblocks, 256, 0, stream>>>(xh, W, ent, out, n);
    } else if (ws_size >= xhB) {
        uint* xh = (uint*)d_ws;
        const int nvec = n * CIN / 8;
        cvt_bf16<<<(nvec + 255) / 256, 256, 0, stream>>>(x, xh, nvec);
        outblock_bf16<<<(n + 255) / 256, 256, 0, stream>>>(xh, W, aprs, lvl, out, n);
    } else {
        outblock_f32<<<(n + 255) / 256, 256, 0, stream>>>(x, W, aprs, lvl, out, n);
    }
}

// Round 12
// 350.998 us; speedup vs baseline: 1.1105x; 1.1105x over previous
//
#include <hip/hip_runtime.h>

// Problem constants (match reference)
constexpr int K    = 27;
constexpr int CIN  = 16;
constexpr int COUT = 4;
constexpr int NS   = 3;
constexpr int WSZ  = K * CIN * COUT;   // 1728 floats per stencil
constexpr int WPAD = WSZ + 8;          // pad for fallback kernel

// Lane-owned chunk-sorted gather configuration (r10-proven sort geometry)
constexpr int NCH  = 32;               // sort chunks: 32K rows = 1MB f16 windows
constexpr int CHSH = 15;               // chunk = nb >> 15 (requires n <= 2^20)
constexpr int NPL  = 4;                // particles per lane
constexpr int NPW  = 256;              // particles per wave
constexpr int RNDS = K * NPL;          // 108 fixed rounds per lane column
constexpr int EPW  = RNDS * 64;        // 6912 entries per wave (column layout)
constexpr unsigned int SENT = 0xFFFFFFFFu;
constexpr int WREG = 34;               // W region stride (dwords), f16 pairs
constexpr int BWAV = 2;                // waves per compute block (fine retirement)

typedef unsigned int uint;
typedef float  f32x4 __attribute__((ext_vector_type(4)));
typedef uint   u32x4 __attribute__((ext_vector_type(4)));
typedef uint   u32x2 __attribute__((ext_vector_type(2)));
typedef _Float16 h16x2 __attribute__((ext_vector_type(2)));

__device__ __forceinline__ uint pkh(float lo, float hi) {
    union { h16x2 h; uint u; } v;
    v.h.x = (_Float16)lo; v.h.y = (_Float16)hi;   // RNE casts
    return v.u;
}
__device__ __forceinline__ h16x2 u2h(uint u) {
    union { uint u; h16x2 h; } v; v.u = u; return v.h;
}

#if defined(__has_builtin)
#if __has_builtin(__builtin_amdgcn_fdot2)
#define HAVE_FDOT2 1
#endif
#endif

__device__ __forceinline__ float dot2acc(uint xp, uint wp, float acc) {
#ifdef HAVE_FDOT2
    return __builtin_amdgcn_fdot2(u2h(xp), u2h(wp), acc, false);
#else
    const h16x2 a = u2h(xp), b = u2h(wp);
    acc = fmaf((float)a.x, (float)b.x, acc);
    return fmaf((float)a.y, (float)b.y, acc);
#endif
}

// bf16 helpers (fallback path only)
__device__ __forceinline__ uint bf16_rne(float f) {
    uint u = __float_as_uint(f);
    u += 0x7FFFu + ((u >> 16) & 1u);
    return u >> 16;
}
__device__ __forceinline__ float blo(uint u) { return __uint_as_float(u << 16); }
__device__ __forceinline__ float bhi(uint u) { return __uint_as_float(u & 0xFFFF0000u); }

// ---- pass 1: x fp32 -> f16 (RNE), packed 2 per dword ----
__global__ __launch_bounds__(256) void cvt_f16(
    const float* __restrict__ x, uint* __restrict__ xh, int nvec)
{
    int i = blockIdx.x * 256 + threadIdx.x;
    if (i >= nvec) return;                 // nvec = N*CIN/8
    const f32x4* xf = reinterpret_cast<const f32x4*>(x) + 2 * (size_t)i;
    f32x4 a = __builtin_nontemporal_load(&xf[0]);
    f32x4 b = __builtin_nontemporal_load(&xf[1]);
    u32x4 o;
    o.x = pkh(a.x, a.y);
    o.y = pkh(a.z, a.w);
    o.z = pkh(b.x, b.y);
    o.w = pkh(b.z, b.w);
    __builtin_nontemporal_store(o, &reinterpret_cast<u32x4*>(xh)[i]);
}

// ---- pass 2: per-LANE counting sort of own 108 taps by x-chunk (r10-proven) ----
// Entry: nb(20)<<9 | b(2)<<7 | s(2)<<5 | j(5). Column layout ent[slot*64+lane].
__global__ __launch_bounds__(64) void bucket_kernel(
    const int* __restrict__ aprs,    // [n, 27]
    const int* __restrict__ lvl,     // [n]
    uint* __restrict__ ent,          // [nwaves, EPW]
    int n)
{
    __shared__ uint stage[EPW];          // 27.6 KB
    __shared__ int  posL[NCH * 64];      // 8 KB cursors

    const int w    = blockIdx.x;
    const int lane = threadIdx.x;
    const int i0   = w * NPW + lane * NPL;
    const int* __restrict__ ap = aprs + (size_t)i0 * K;

    #pragma unroll
    for (int c = 0; c < NCH; ++c) posL[c * 64 + lane] = 0;
    for (int t = 0; t < RNDS; ++t) stage[t * 64 + lane] = SENT;

    // histogram of this lane's taps
    for (int b = 0; b < NPL; ++b) {
        if (i0 + b < n) {
            for (int j = 0; j < K; ++j) {
                const int ch = (int)(((uint)ap[b * K + j]) >> CHSH);
                posL[ch * 64 + lane] += 1;
            }
        }
    }
    // per-lane exclusive prefix (serial over 32 cells)
    int run = 0;
    #pragma unroll
    for (int c = 0; c < NCH; ++c) {
        const int cc = posL[c * 64 + lane];
        posL[c * 64 + lane] = run;
        run += cc;
    }
    // emit chunk-sorted entries into own column (aprs re-read hits L1/L2)
    for (int b = 0; b < NPL; ++b) {
        if (i0 + b < n) {
            const uint s = (uint)lvl[i0 + b];
            const uint tag = ((uint)b << 7) | (s << 5);
            for (int j = 0; j < K; ++j) {
                const uint nb = (uint)ap[b * K + j];
                const int ch  = (int)(nb >> CHSH);
                const int slot = posL[ch * 64 + lane];
                posL[ch * 64 + lane] = slot + 1;
                stage[slot * 64 + lane] = (nb << 9) | tag | (uint)j;
            }
        }
    }
    // dump own column (coalesced across lanes)
    uint* __restrict__ eb = ent + (size_t)w * EPW;
    for (int t = 0; t < RNDS; ++t) eb[t * 64 + lane] = stage[t * 64 + lane];
}

// ---- pass 3: free-running 108-round gather, 4-deep pipeline, f16 dot2 ----
// 2-wave blocks: finer retirement granularity; 8 blocks/CU, 16 waves/CU ceiling.
__global__ __launch_bounds__(BWAV * 64, 4) void compute_kernel(
    const uint*  __restrict__ xh,    // [n, 8] dwords (16 f16)
    const float* __restrict__ Wg,    // [3, 27, 16, 4] f32
    const uint*  __restrict__ ent,   // [nwaves, EPW]
    float*       __restrict__ out,   // [n, 4]
    int n)
{
    // W repacked for dot2: region sk -> dword (q*8+p) = f16 pair (W[2p][q], W[2p+1][q])
    __shared__ __align__(8) uint Wb[NS * K * WREG];   // 81 * 34 dwords = 11 KB

    const int tid = threadIdx.x;
    for (int idx = tid; idx < NS * K * 32; idx += BWAV * 64) {
        const int reg = idx >> 5, g = idx & 31;
        const int q = g >> 3, p = g & 7;
        Wb[reg * WREG + g] = pkh(Wg[reg * 64 + 8 * p + q],
                                 Wg[reg * 64 + 8 * p + 4 + q]);
    }
    __syncthreads();

    const int widx = tid >> 6, lane = tid & 63;
    const int w = blockIdx.x * BWAV + widx;
    const uint* __restrict__ eb = ent + (size_t)w * EPW;

    f32x4 A0 = {0,0,0,0}, A1 = {0,0,0,0}, A2 = {0,0,0,0}, A3 = {0,0,0,0};

    // prime 4-deep pipeline: entries s..s+3; x for s, s+1, s+2 in flight
    uint e0 = eb[lane];
    uint e1 = eb[64 + lane];
    uint e2 = eb[128 + lane];
    uint e3 = eb[192 + lane];
    {
        const uint nb0 = (e0 == SENT) ? 0u : (e0 >> 9);
        const u32x4* __restrict__ xr0 =
            reinterpret_cast<const u32x4*>(xh + (size_t)nb0 * 8);
        u32x4 X0a = xr0[0];
        u32x4 X0b = xr0[1];
        const uint nb1 = (e1 == SENT) ? 0u : (e1 >> 9);
        const u32x4* __restrict__ xr1 =
            reinterpret_cast<const u32x4*>(xh + (size_t)nb1 * 8);
        u32x4 X1a = xr1[0];
        u32x4 X1b = xr1[1];
        const uint nb2 = (e2 == SENT) ? 0u : (e2 >> 9);
        const u32x4* __restrict__ xr2 =
            reinterpret_cast<const u32x4*>(xh + (size_t)nb2 * 8);
        u32x4 X2a = xr2[0];
        u32x4 X2b = xr2[1];

        for (int s = 0; s < RNDS; ++s) {
            // (1) entry prefetch for slot s+4
            const int sF = (s + 4 < RNDS) ? s + 4 : RNDS - 1;
            const uint eF = eb[(size_t)sF * 64 + lane];
            // (2) x prefetch for slot s+3
            const uint nb3 = (e3 == SENT) ? 0u : (e3 >> 9);
            const u32x4* __restrict__ xr3 =
                reinterpret_cast<const u32x4*>(xh + (size_t)nb3 * 8);
            const u32x4 X3a = xr3[0];
            const u32x4 X3b = xr3[1];

            // (3) compute slot s
            const bool valid = (e0 != SENT);
            const uint bq  = (e0 >> 7) & 3u;
            const uint skr = ((e0 >> 5) & 3u) * (uint)K + (e0 & 31u);
            const uint sk  = valid ? skr : 0u;
            const uint* __restrict__ wr = &Wb[sk * WREG];

            uint xd[8];
            xd[0] = X0a.x; xd[1] = X0a.y; xd[2] = X0a.z; xd[3] = X0a.w;
            xd[4] = X0b.x; xd[5] = X0b.y; xd[6] = X0b.z; xd[7] = X0b.w;

            float pq0 = 0.f, pq1 = 0.f, pq2 = 0.f, pq3 = 0.f;
            #pragma unroll
            for (int t = 0; t < 4; ++t) {
                const u32x2 w0 = *reinterpret_cast<const u32x2*>(wr +  0 + 2 * t);
                const u32x2 w1 = *reinterpret_cast<const u32x2*>(wr +  8 + 2 * t);
                const u32x2 w2 = *reinterpret_cast<const u32x2*>(wr + 16 + 2 * t);
                const u32x2 w3 = *reinterpret_cast<const u32x2*>(wr + 24 + 2 * t);
                pq0 = dot2acc(xd[2 * t], w0.x, pq0);
                pq0 = dot2acc(xd[2 * t + 1], w0.y, pq0);
                pq1 = dot2acc(xd[2 * t], w1.x, pq1);
                pq1 = dot2acc(xd[2 * t + 1], w1.y, pq1);
                pq2 = dot2acc(xd[2 * t], w2.x, pq2);
                pq2 = dot2acc(xd[2 * t + 1], w2.y, pq2);
                pq3 = dot2acc(xd[2 * t], w3.x, pq3);
                pq3 = dot2acc(xd[2 * t + 1], w3.y, pq3);
            }
            const float m0 = (valid && bq == 0u) ? 1.f : 0.f;
            const float m1 = (valid && bq == 1u) ? 1.f : 0.f;
            const float m2 = (valid && bq == 2u) ? 1.f : 0.f;
            const float m3 = (valid && bq == 3u) ? 1.f : 0.f;
            A0.x = fmaf(m0, pq0, A0.x); A0.y = fmaf(m0, pq1, A0.y);
            A0.z = fmaf(m0, pq2, A0.z); A0.w = fmaf(m0, pq3, A0.w);
            A1.x = fmaf(m1, pq0, A1.x); A1.y = fmaf(m1, pq1, A1.y);
            A1.z = fmaf(m1, pq2, A1.z); A1.w = fmaf(m1, pq3, A1.w);
            A2.x = fmaf(m2, pq0, A2.x); A2.y = fmaf(m2, pq1, A2.y);
            A2.z = fmaf(m2, pq2, A2.z); A2.w = fmaf(m2, pq3, A2.w);
            A3.x = fmaf(m3, pq0, A3.x); A3.y = fmaf(m3, pq1, A3.y);
            A3.z = fmaf(m3, pq2, A3.z); A3.w = fmaf(m3, pq3, A3.w);

            // rotate 4-deep pipeline
            e0 = e1; X0a = X1a; X0b = X1b;
            e1 = e2; X1a = X2a; X1b = X2b;
            e2 = e3; X2a = X3a; X2b = X3b;
            e3 = eF;
        }
    }

    // epilogue: relu + per-lane 64B contiguous stores
    const int i0 = w * NPW + lane * NPL;
    f32x4* __restrict__ op = reinterpret_cast<f32x4*>(out);
    f32x4 o;
    if (i0 + 0 < n) {
        o.x = fmaxf(A0.x,0.f); o.y = fmaxf(A0.y,0.f); o.z = fmaxf(A0.z,0.f); o.w = fmaxf(A0.w,0.f);
        __builtin_nontemporal_store(o, op + i0 + 0);
    }
    if (i0 + 1 < n) {
        o.x = fmaxf(A1.x,0.f); o.y = fmaxf(A1.y,0.f); o.z = fmaxf(A1.z,0.f); o.w = fmaxf(A1.w,0.f);
        __builtin_nontemporal_store(o, op + i0 + 1);
    }
    if (i0 + 2 < n) {
        o.x = fmaxf(A2.x,0.f); o.y = fmaxf(A2.y,0.f); o.z = fmaxf(A2.z,0.f); o.w = fmaxf(A2.w,0.f);
        __builtin_nontemporal_store(o, op + i0 + 2);
    }
    if (i0 + 3 < n) {
        o.x = fmaxf(A3.x,0.f); o.y = fmaxf(A3.y,0.f); o.z = fmaxf(A3.z,0.f); o.w = fmaxf(A3.w,0.f);
        __builtin_nontemporal_store(o, op + i0 + 3);
    }
}

// ---- fallback chain (bf16 flat gather, r4-proven) ----
__global__ __launch_bounds__(256) void cvt_bf16(
    const float* __restrict__ x, uint* __restrict__ xh, int nvec)
{
    int i = blockIdx.x * 256 + threadIdx.x;
    if (i >= nvec) return;
    const f32x4* xf = reinterpret_cast<const f32x4*>(x) + 2 * (size_t)i;
    f32x4 a = __builtin_nontemporal_load(&xf[0]);
    f32x4 b = __builtin_nontemporal_load(&xf[1]);
    u32x4 o;
    o.x = bf16_rne(a.x) | (bf16_rne(a.y) << 16);
    o.y = bf16_rne(a.z) | (bf16_rne(a.w) << 16);
    o.z = bf16_rne(b.x) | (bf16_rne(b.y) << 16);
    o.w = bf16_rne(b.z) | (bf16_rne(b.w) << 16);
    __builtin_nontemporal_store(o, &reinterpret_cast<u32x4*>(xh)[i]);
}

__global__ __launch_bounds__(256) void outblock_bf16(
    const uint*  __restrict__ xh,
    const float* __restrict__ W,
    const int*   __restrict__ aprs,
    const int*   __restrict__ lvl,
    float*       __restrict__ out,
    int n)
{
    __shared__ float Wl[NS * WPAD];
    for (int i = threadIdx.x; i < NS * WSZ; i += 256) {
        int s = i / WSZ;
        Wl[s * WPAD + (i - s * WSZ)] = W[i];
    }
    __syncthreads();

    int nIdx = blockIdx.x * 256 + threadIdx.x;
    if (nIdx >= n) return;

    const int s = lvl[nIdx];
    const float* __restrict__ Ws = &Wl[s * WPAD];
    const int*   __restrict__ ap = aprs + (size_t)nIdx * K;

    float a0 = 0.f, a1 = 0.f, a2 = 0.f, a3 = 0.f;
    #pragma unroll 3
    for (int k = 0; k < K; ++k) {
        const int nb = ap[k];
        const u32x4* __restrict__ xr =
            reinterpret_cast<const u32x4*>(xh + (size_t)nb * 8);
        const u32x4 p0 = xr[0];
        const u32x4 p1 = xr[1];
        const float* __restrict__ Wk = Ws + k * (CIN * COUT);
        float xv[16];
        xv[ 0] = blo(p0.x); xv[ 1] = bhi(p0.x);
        xv[ 2] = blo(p0.y); xv[ 3] = bhi(p0.y);
        xv[ 4] = blo(p0.z); xv[ 5] = bhi(p0.z);
        xv[ 6] = blo(p0.w); xv[ 7] = bhi(p0.w);
        xv[ 8] = blo(p1.x); xv[ 9] = bhi(p1.x);
        xv[10] = blo(p1.y); xv[11] = bhi(p1.y);
        xv[12] = blo(p1.z); xv[13] = bhi(p1.z);
        xv[14] = blo(p1.w); xv[15] = bhi(p1.w);
        #pragma unroll
        for (int cq = 0; cq < CIN; ++cq) {
            const float4 wv = *reinterpret_cast<const float4*>(&Wk[cq * COUT]);
            a0 = fmaf(xv[cq], wv.x, a0);
            a1 = fmaf(xv[cq], wv.y, a1);
            a2 = fmaf(xv[cq], wv.z, a2);
            a3 = fmaf(xv[cq], wv.w, a3);
        }
    }
    f32x4 o;
    o.x = fmaxf(a0, 0.f); o.y = fmaxf(a1, 0.f);
    o.z = fmaxf(a2, 0.f); o.w = fmaxf(a3, 0.f);
    __builtin_nontemporal_store(o, reinterpret_cast<f32x4*>(out) + nIdx);
}

__global__ __launch_bounds__(256) void outblock_f32(
    const float* __restrict__ x,
    const float* __restrict__ W,
    const int*   __restrict__ aprs,
    const int*   __restrict__ lvl,
    float*       __restrict__ out,
    int n)
{
    __shared__ float Wl[NS * WPAD];
    for (int i = threadIdx.x; i < NS * WSZ; i += 256) {
        int s = i / WSZ;
        Wl[s * WPAD + (i - s * WSZ)] = W[i];
    }
    __syncthreads();
    int nIdx = blockIdx.x * 256 + threadIdx.x;
    if (nIdx >= n) return;
    const int s = lvl[nIdx];
    const float* __restrict__ Ws = &Wl[s * WPAD];
    const int*   __restrict__ ap = aprs + (size_t)nIdx * K;
    float a0 = 0.f, a1 = 0.f, a2 = 0.f, a3 = 0.f;
    #pragma unroll 3
    for (int k = 0; k < K; ++k) {
        const int nb = ap[k];
        const float4* __restrict__ xr =
            reinterpret_cast<const float4*>(x + (size_t)nb * CIN);
        const float4 v0 = xr[0], v1 = xr[1], v2 = xr[2], v3 = xr[3];
        const float* __restrict__ Wk = Ws + k * (CIN * COUT);
        float xv[16];
        xv[ 0] = v0.x; xv[ 1] = v0.y; xv[ 2] = v0.z; xv[ 3] = v0.w;
        xv[ 4] = v1.x; xv[ 5] = v1.y; xv[ 6] = v1.z; xv[ 7] = v1.w;
        xv[ 8] = v2.x; xv[ 9] = v2.y; xv[10] = v2.z; xv[11] = v2.w;
        xv[12] = v3.x; xv[13] = v3.y; xv[14] = v3.z; xv[15] = v3.w;
        #pragma unroll
        for (int cq = 0; cq < CIN; ++cq) {
            const float4 wv = *reinterpret_cast<const float4*>(&Wk[cq * COUT]);
            a0 = fmaf(xv[cq], wv.x, a0);
            a1 = fmaf(xv[cq], wv.y, a1);
            a2 = fmaf(xv[cq], wv.z, a2);
            a3 = fmaf(xv[cq], wv.w, a3);
        }
    }
    float4 o;
    o.x = fmaxf(a0, 0.f); o.y = fmaxf(a1, 0.f);
    o.z = fmaxf(a2, 0.f); o.w = fmaxf(a3, 0.f);
    reinterpret_cast<float4*>(out)[nIdx] = o;
}

extern "C" void kernel_launch(void* const* d_in, const int* in_sizes, int n_in,
                              void* d_out, int out_size, void* d_ws, size_t ws_size,
                              hipStream_t stream) {
    const float* x    = (const float*)d_in[0];
    const float* W    = (const float*)d_in[1];
    const int*   aprs = (const int*)d_in[2];
    const int*   lvl  = (const int*)d_in[3];
    float*       out  = (float*)d_out;

    const int n = in_sizes[0] / CIN;               // N particles

    const int nwaves    = (n + NPW - 1) / NPW;
    const int nblocks   = (nwaves + BWAV - 1) / BWAV;
    const int nwavesPad = nblocks * BWAV;

    const size_t xhB  = (size_t)n * CIN * 2;             // 32 MB f16 x copy
    const size_t entB = (size_t)nwavesPad * EPW * 4;     // ~113 MB entries
    const size_t needChunked = xhB + entB;

    if (ws_size >= needChunked && n <= (1 << 20)) {
        uint* xh  = (uint*)d_ws;
        uint* ent = (uint*)((char*)d_ws + xhB);
        const int nvec = n * CIN / 8;
        cvt_f16<<<(nvec + 255) / 256, 256, 0, stream>>>(x, xh, nvec);
        bucket_kernel<<<nwavesPad, 64, 0, stream>>>(aprs, lvl, ent, n);
        compute_kernel<<<nblocks, BWAV * 64, 0, stream>>>(xh, W, ent, out, n);
    } else if (ws_size >= xhB) {
        uint* xh = (uint*)d_ws;
        const int nvec = n * CIN / 8;
        cvt_bf16<<<(nvec + 255) / 256, 256, 0, stream>>>(x, xh, nvec);
        outblock_bf16<<<(n + 255) / 256, 256, 0, stream>>>(xh, W, aprs, lvl, out, n);
    } else {
        outblock_f32<<<(n + 255) / 256, 256, 0, stream>>>(x, W, aprs, lvl, out, n);
    }
}

// Round 13
// 306.189 us; speedup vs baseline: 1.2730x; 1.1463x over previous
//
#include <hip/hip_runtime.h>

// Problem constants (match reference)
constexpr int K    = 27;
constexpr int CIN  = 16;
constexpr int COUT = 4;
constexpr int NS   = 3;
constexpr int WSZ  = K * CIN * COUT;   // 1728 floats per stencil
constexpr int WPAD = WSZ + 8;          // pad for fallback kernel

// Lane-owned chunk-sorted gather configuration (r10-proven geometry)
constexpr int NCH  = 32;               // sort chunks: 32K rows = 1MB f16 windows
constexpr int CHSH = 15;               // chunk = nb >> 15 (requires n <= 2^20)
constexpr int NPL  = 4;                // particles per lane
constexpr int NPW  = 256;              // particles per wave
constexpr int RNDS = K * NPL;          // 108 fixed rounds per lane column
constexpr int EPW  = RNDS * 64;        // 6912 entries per wave (column layout)
constexpr unsigned int SENT = 0xFFFFFFFFu;
constexpr int WREG = 34;               // W region stride (dwords), f16 pairs
constexpr int BWAV = 4;                // waves per compute block (r10-proven blocking)

typedef unsigned int uint;
typedef float  f32x4 __attribute__((ext_vector_type(4)));
typedef uint   u32x4 __attribute__((ext_vector_type(4)));
typedef uint   u32x2 __attribute__((ext_vector_type(2)));
typedef _Float16 h16x2 __attribute__((ext_vector_type(2)));

__device__ __forceinline__ uint pkh(float lo, float hi) {
    union { h16x2 h; uint u; } v;
    v.h.x = (_Float16)lo; v.h.y = (_Float16)hi;   // RNE casts
    return v.u;
}
__device__ __forceinline__ h16x2 u2h(uint u) {
    union { uint u; h16x2 h; } v; v.u = u; return v.h;
}

#if defined(__has_builtin)
#if __has_builtin(__builtin_amdgcn_fdot2)
#define HAVE_FDOT2 1
#endif
#endif

__device__ __forceinline__ float dot2acc(uint xp, uint wp, float acc) {
#ifdef HAVE_FDOT2
    return __builtin_amdgcn_fdot2(u2h(xp), u2h(wp), acc, false);
#else
    const h16x2 a = u2h(xp), b = u2h(wp);
    acc = fmaf((float)a.x, (float)b.x, acc);
    return fmaf((float)a.y, (float)b.y, acc);
#endif
}

// bf16 helpers (fallback path only)
__device__ __forceinline__ uint bf16_rne(float f) {
    uint u = __float_as_uint(f);
    u += 0x7FFFu + ((u >> 16) & 1u);
    return u >> 16;
}
__device__ __forceinline__ float blo(uint u) { return __uint_as_float(u << 16); }
__device__ __forceinline__ float bhi(uint u) { return __uint_as_float(u & 0xFFFF0000u); }

// ---- pass 1: x fp32 -> f16 (RNE), packed 2 per dword ----
__global__ __launch_bounds__(256) void cvt_f16(
    const float* __restrict__ x, uint* __restrict__ xh, int nvec)
{
    int i = blockIdx.x * 256 + threadIdx.x;
    if (i >= nvec) return;                 // nvec = N*CIN/8
    const f32x4* xf = reinterpret_cast<const f32x4*>(x) + 2 * (size_t)i;
    f32x4 a = __builtin_nontemporal_load(&xf[0]);
    f32x4 b = __builtin_nontemporal_load(&xf[1]);
    u32x4 o;
    o.x = pkh(a.x, a.y);
    o.y = pkh(a.z, a.w);
    o.z = pkh(b.x, b.y);
    o.w = pkh(b.z, b.w);
    __builtin_nontemporal_store(o, &reinterpret_cast<u32x4*>(xh)[i]);
}

// ---- pass 2: per-LANE counting sort of own 108 taps by x-chunk (r10-proven) ----
// Entry: nb(20)<<9 | b(2)<<7 | s(2)<<5 | j(5). Column layout ent[slot*64+lane].
__global__ __launch_bounds__(64) void bucket_kernel(
    const int* __restrict__ aprs,    // [n, 27]
    const int* __restrict__ lvl,     // [n]
    uint* __restrict__ ent,          // [nwaves, EPW]
    int n)
{
    __shared__ uint stage[EPW];          // 27.6 KB
    __shared__ int  posL[NCH * 64];      // 8 KB cursors

    const int w    = blockIdx.x;
    const int lane = threadIdx.x;
    const int i0   = w * NPW + lane * NPL;
    const int* __restrict__ ap = aprs + (size_t)i0 * K;

    #pragma unroll
    for (int c = 0; c < NCH; ++c) posL[c * 64 + lane] = 0;
    for (int t = 0; t < RNDS; ++t) stage[t * 64 + lane] = SENT;

    // histogram of this lane's taps
    for (int b = 0; b < NPL; ++b) {
        if (i0 + b < n) {
            for (int j = 0; j < K; ++j) {
                const int ch = (int)(((uint)ap[b * K + j]) >> CHSH);
                posL[ch * 64 + lane] += 1;
            }
        }
    }
    // per-lane exclusive prefix (serial over 32 cells)
    int run = 0;
    #pragma unroll
    for (int c = 0; c < NCH; ++c) {
        const int cc = posL[c * 64 + lane];
        posL[c * 64 + lane] = run;
        run += cc;
    }
    // emit chunk-sorted entries into own column (aprs re-read hits L1/L2)
    for (int b = 0; b < NPL; ++b) {
        if (i0 + b < n) {
            const uint s = (uint)lvl[i0 + b];
            const uint tag = ((uint)b << 7) | (s << 5);
            for (int j = 0; j < K; ++j) {
                const uint nb = (uint)ap[b * K + j];
                const int ch  = (int)(nb >> CHSH);
                const int slot = posL[ch * 64 + lane];
                posL[ch * 64 + lane] = slot + 1;
                stage[slot * 64 + lane] = (nb << 9) | tag | (uint)j;
            }
        }
    }
    // dump own column (coalesced across lanes)
    uint* __restrict__ eb = ent + (size_t)w * EPW;
    for (int t = 0; t < RNDS; ++t) eb[t * 64 + lane] = stage[t * 64 + lane];
}

// ---- pass 3: free-running 108-round gather, 4-deep pipeline, f16 dot2 ----
// r10 blocking: 4 waves/block, 1024 blocks = 4 blocks/CU. ONLY change: depth 3->4.
__global__ __launch_bounds__(BWAV * 64, 4) void compute_kernel(
    const uint*  __restrict__ xh,    // [n, 8] dwords (16 f16)
    const float* __restrict__ Wg,    // [3, 27, 16, 4] f32
    const uint*  __restrict__ ent,   // [nwaves, EPW]
    float*       __restrict__ out,   // [n, 4]
    int n)
{
    // W repacked for dot2: region sk -> dword (q*8+p) = f16 pair (W[2p][q], W[2p+1][q])
    __shared__ __align__(8) uint Wb[NS * K * WREG];   // 81 * 34 dwords = 11 KB

    const int tid = threadIdx.x;
    for (int idx = tid; idx < NS * K * 32; idx += BWAV * 64) {
        const int reg = idx >> 5, g = idx & 31;
        const int q = g >> 3, p = g & 7;
        Wb[reg * WREG + g] = pkh(Wg[reg * 64 + 8 * p + q],
                                 Wg[reg * 64 + 8 * p + 4 + q]);
    }
    __syncthreads();

    const int widx = tid >> 6, lane = tid & 63;
    const int w = blockIdx.x * BWAV + widx;
    const uint* __restrict__ eb = ent + (size_t)w * EPW;

    f32x4 A0 = {0,0,0,0}, A1 = {0,0,0,0}, A2 = {0,0,0,0}, A3 = {0,0,0,0};

    // prime 4-deep pipeline: entries s..s+3; x for s, s+1, s+2 in flight
    uint e0 = eb[lane];
    uint e1 = eb[64 + lane];
    uint e2 = eb[128 + lane];
    uint e3 = eb[192 + lane];
    {
        const uint nb0 = (e0 == SENT) ? 0u : (e0 >> 9);
        const u32x4* __restrict__ xr0 =
            reinterpret_cast<const u32x4*>(xh + (size_t)nb0 * 8);
        u32x4 X0a = xr0[0];
        u32x4 X0b = xr0[1];
        const uint nb1 = (e1 == SENT) ? 0u : (e1 >> 9);
        const u32x4* __restrict__ xr1 =
            reinterpret_cast<const u32x4*>(xh + (size_t)nb1 * 8);
        u32x4 X1a = xr1[0];
        u32x4 X1b = xr1[1];
        const uint nb2 = (e2 == SENT) ? 0u : (e2 >> 9);
        const u32x4* __restrict__ xr2 =
            reinterpret_cast<const u32x4*>(xh + (size_t)nb2 * 8);
        u32x4 X2a = xr2[0];
        u32x4 X2b = xr2[1];

        for (int s = 0; s < RNDS; ++s) {
            // (1) entry prefetch for slot s+4
            const int sF = (s + 4 < RNDS) ? s + 4 : RNDS - 1;
            const uint eF = eb[(size_t)sF * 64 + lane];
            // (2) x prefetch for slot s+3
            const uint nb3 = (e3 == SENT) ? 0u : (e3 >> 9);
            const u32x4* __restrict__ xr3 =
                reinterpret_cast<const u32x4*>(xh + (size_t)nb3 * 8);
            const u32x4 X3a = xr3[0];
            const u32x4 X3b = xr3[1];

            // (3) compute slot s
            const bool valid = (e0 != SENT);
            const uint bq  = (e0 >> 7) & 3u;
            const uint skr = ((e0 >> 5) & 3u) * (uint)K + (e0 & 31u);
            const uint sk  = valid ? skr : 0u;
            const uint* __restrict__ wr = &Wb[sk * WREG];

            uint xd[8];
            xd[0] = X0a.x; xd[1] = X0a.y; xd[2] = X0a.z; xd[3] = X0a.w;
            xd[4] = X0b.x; xd[5] = X0b.y; xd[6] = X0b.z; xd[7] = X0b.w;

            float pq0 = 0.f, pq1 = 0.f, pq2 = 0.f, pq3 = 0.f;
            #pragma unroll
            for (int t = 0; t < 4; ++t) {
                const u32x2 w0 = *reinterpret_cast<const u32x2*>(wr +  0 + 2 * t);
                const u32x2 w1 = *reinterpret_cast<const u32x2*>(wr +  8 + 2 * t);
                const u32x2 w2 = *reinterpret_cast<const u32x2*>(wr + 16 + 2 * t);
                const u32x2 w3 = *reinterpret_cast<const u32x2*>(wr + 24 + 2 * t);
                pq0 = dot2acc(xd[2 * t], w0.x, pq0);
                pq0 = dot2acc(xd[2 * t + 1], w0.y, pq0);
                pq1 = dot2acc(xd[2 * t], w1.x, pq1);
                pq1 = dot2acc(xd[2 * t + 1], w1.y, pq1);
                pq2 = dot2acc(xd[2 * t], w2.x, pq2);
                pq2 = dot2acc(xd[2 * t + 1], w2.y, pq2);
                pq3 = dot2acc(xd[2 * t], w3.x, pq3);
                pq3 = dot2acc(xd[2 * t + 1], w3.y, pq3);
            }
            const float m0 = (valid && bq == 0u) ? 1.f : 0.f;
            const float m1 = (valid && bq == 1u) ? 1.f : 0.f;
            const float m2 = (valid && bq == 2u) ? 1.f : 0.f;
            const float m3 = (valid && bq == 3u) ? 1.f : 0.f;
            A0.x = fmaf(m0, pq0, A0.x); A0.y = fmaf(m0, pq1, A0.y);
            A0.z = fmaf(m0, pq2, A0.z); A0.w = fmaf(m0, pq3, A0.w);
            A1.x = fmaf(m1, pq0, A1.x); A1.y = fmaf(m1, pq1, A1.y);
            A1.z = fmaf(m1, pq2, A1.z); A1.w = fmaf(m1, pq3, A1.w);
            A2.x = fmaf(m2, pq0, A2.x); A2.y = fmaf(m2, pq1, A2.y);
            A2.z = fmaf(m2, pq2, A2.z); A2.w = fmaf(m2, pq3, A2.w);
            A3.x = fmaf(m3, pq0, A3.x); A3.y = fmaf(m3, pq1, A3.y);
            A3.z = fmaf(m3, pq2, A3.z); A3.w = fmaf(m3, pq3, A3.w);

            // rotate 4-deep pipeline
            e0 = e1; X0a = X1a; X0b = X1b;
            e1 = e2; X1a = X2a; X1b = X2b;
            e2 = e3; X2a = X3a; X2b = X3b;
            e3 = eF;
        }
    }

    // epilogue: relu + per-lane 64B contiguous stores
    const int i0 = w * NPW + lane * NPL;
    f32x4* __restrict__ op = reinterpret_cast<f32x4*>(out);
    f32x4 o;
    if (i0 + 0 < n) {
        o.x = fmaxf(A0.x,0.f); o.y = fmaxf(A0.y,0.f); o.z = fmaxf(A0.z,0.f); o.w = fmaxf(A0.w,0.f);
        __builtin_nontemporal_store(o, op + i0 + 0);
    }
    if (i0 + 1 < n) {
        o.x = fmaxf(A1.x,0.f); o.y = fmaxf(A1.y,0.f); o.z = fmaxf(A1.z,0.f); o.w = fmaxf(A1.w,0.f);
        __builtin_nontemporal_store(o, op + i0 + 1);
    }
    if (i0 + 2 < n) {
        o.x = fmaxf(A2.x,0.f); o.y = fmaxf(A2.y,0.f); o.z = fmaxf(A2.z,0.f); o.w = fmaxf(A2.w,0.f);
        __builtin_nontemporal_store(o, op + i0 + 2);
    }
    if (i0 + 3 < n) {
        o.x = fmaxf(A3.x,0.f); o.y = fmaxf(A3.y,0.f); o.z = fmaxf(A3.z,0.f); o.w = fmaxf(A3.w,0.f);
        __builtin_nontemporal_store(o, op + i0 + 3);
    }
}

// ---- fallback chain (bf16 flat gather, r4-proven) ----
__global__ __launch_bounds__(256) void cvt_bf16(
    const float* __restrict__ x, uint* __restrict__ xh, int nvec)
{
    int i = blockIdx.x * 256 + threadIdx.x;
    if (i >= nvec) return;
    const f32x4* xf = reinterpret_cast<const f32x4*>(x) + 2 * (size_t)i;
    f32x4 a = __builtin_nontemporal_load(&xf[0]);
    f32x4 b = __builtin_nontemporal_load(&xf[1]);
    u32x4 o;
    o.x = bf16_rne(a.x) | (bf16_rne(a.y) << 16);
    o.y = bf16_rne(a.z) | (bf16_rne(a.w) << 16);
    o.z = bf16_rne(b.x) | (bf16_rne(b.y) << 16);
    o.w = bf16_rne(b.z) | (bf16_rne(b.w) << 16);
    __builtin_nontemporal_store(o, &reinterpret_cast<u32x4*>(xh)[i]);
}

__global__ __launch_bounds__(256) void outblock_bf16(
    const uint*  __restrict__ xh,
    const float* __restrict__ W,
    const int*   __restrict__ aprs,
    const int*   __restrict__ lvl,
    float*       __restrict__ out,
    int n)
{
    __shared__ float Wl[NS * WPAD];
    for (int i = threadIdx.x; i < NS * WSZ; i += 256) {
        int s = i / WSZ;
        Wl[s * WPAD + (i - s * WSZ)] = W[i];
    }
    __syncthreads();

    int nIdx = blockIdx.x * 256 + threadIdx.x;
    if (nIdx >= n) return;

    const int s = lvl[nIdx];
    const float* __restrict__ Ws = &Wl[s * WPAD];
    const int*   __restrict__ ap = aprs + (size_t)nIdx * K;

    float a0 = 0.f, a1 = 0.f, a2 = 0.f, a3 = 0.f;
    #pragma unroll 3
    for (int k = 0; k < K; ++k) {
        const int nb = ap[k];
        const u32x4* __restrict__ xr =
            reinterpret_cast<const u32x4*>(xh + (size_t)nb * 8);
        const u32x4 p0 = xr[0];
        const u32x4 p1 = xr[1];
        const float* __restrict__ Wk = Ws + k * (CIN * COUT);
        float xv[16];
        xv[ 0] = blo(p0.x); xv[ 1] = bhi(p0.x);
        xv[ 2] = blo(p0.y); xv[ 3] = bhi(p0.y);
        xv[ 4] = blo(p0.z); xv[ 5] = bhi(p0.z);
        xv[ 6] = blo(p0.w); xv[ 7] = bhi(p0.w);
        xv[ 8] = blo(p1.x); xv[ 9] = bhi(p1.x);
        xv[10] = blo(p1.y); xv[11] = bhi(p1.y);
        xv[12] = blo(p1.z); xv[13] = bhi(p1.z);
        xv[14] = blo(p1.w); xv[15] = bhi(p1.w);
        #pragma unroll
        for (int cq = 0; cq < CIN; ++cq) {
            const float4 wv = *reinterpret_cast<const float4*>(&Wk[cq * COUT]);
            a0 = fmaf(xv[cq], wv.x, a0);
            a1 = fmaf(xv[cq], wv.y, a1);
            a2 = fmaf(xv[cq], wv.z, a2);
            a3 = fmaf(xv[cq], wv.w, a3);
        }
    }
    f32x4 o;
    o.x = fmaxf(a0, 0.f); o.y = fmaxf(a1, 0.f);
    o.z = fmaxf(a2, 0.f); o.w = fmaxf(a3, 0.f);
    __builtin_nontemporal_store(o, reinterpret_cast<f32x4*>(out) + nIdx);
}

__global__ __launch_bounds__(256) void outblock_f32(
    const float* __restrict__ x,
    const float* __restrict__ W,
    const int*   __restrict__ aprs,
    const int*   __restrict__ lvl,
    float*       __restrict__ out,
    int n)
{
    __shared__ float Wl[NS * WPAD];
    for (int i = threadIdx.x; i < NS * WSZ; i += 256) {
        int s = i / WSZ;
        Wl[s * WPAD + (i - s * WSZ)] = W[i];
    }
    __syncthreads();
    int nIdx = blockIdx.x * 256 + threadIdx.x;
    if (nIdx >= n) return;
    const int s = lvl[nIdx];
    const float* __restrict__ Ws = &Wl[s * WPAD];
    const int*   __restrict__ ap = aprs + (size_t)nIdx * K;
    float a0 = 0.f, a1 = 0.f, a2 = 0.f, a3 = 0.f;
    #pragma unroll 3
    for (int k = 0; k < K; ++k) {
        const int nb = ap[k];
        const float4* __restrict__ xr =
            reinterpret_cast<const float4*>(x + (size_t)nb * CIN);
        const float4 v0 = xr[0], v1 = xr[1], v2 = xr[2], v3 = xr[3];
        const float* __restrict__ Wk = Ws + k * (CIN * COUT);
        float xv[16];
        xv[ 0] = v0.x; xv[ 1] = v0.y; xv[ 2] = v0.z; xv[ 3] = v0.w;
        xv[ 4] = v1.x; xv[ 5] = v1.y; xv[ 6] = v1.z; xv[ 7] = v1.w;
        xv[ 8] = v2.x; xv[ 9] = v2.y; xv[10] = v2.z; xv[11] = v2.w;
        xv[12] = v3.x; xv[13] = v3.y; xv[14] = v3.z; xv[15] = v3.w;
        #pragma unroll
        for (int cq = 0; cq < CIN; ++cq) {
            const float4 wv = *reinterpret_cast<const float4*>(&Wk[cq * COUT]);
            a0 = fmaf(xv[cq], wv.x, a0);
            a1 = fmaf(xv[cq], wv.y, a1);
            a2 = fmaf(xv[cq], wv.z, a2);
            a3 = fmaf(xv[cq], wv.w, a3);
        }
    }
    float4 o;
    o.x = fmaxf(a0, 0.f); o.y = fmaxf(a1, 0.f);
    o.z = fmaxf(a2, 0.f); o.w = fmaxf(a3, 0.f);
    reinterpret_cast<float4*>(out)[nIdx] = o;
}

extern "C" void kernel_launch(void* const* d_in, const int* in_sizes, int n_in,
                              void* d_out, int out_size, void* d_ws, size_t ws_size,
                              hipStream_t stream) {
    const float* x    = (const float*)d_in[0];
    const float* W    = (const float*)d_in[1];
    const int*   aprs = (const int*)d_in[2];
    const int*   lvl  = (const int*)d_in[3];
    float*       out  = (float*)d_out;

    const int n = in_sizes[0] / CIN;               // N particles

    const int nwaves    = (n + NPW - 1) / NPW;
    const int nblocks   = (nwaves + BWAV - 1) / BWAV;
    const int nwavesPad = nblocks * BWAV;

    const size_t xhB  = (size_t)n * CIN * 2;             // 32 MB f16 x copy
    const size_t entB = (size_t)nwavesPad * EPW * 4;     // ~113 MB entries
    const size_t needChunked = xhB + entB;

    if (ws_size >= needChunked && n <= (1 << 20)) {
        uint* xh  = (uint*)d_ws;
        uint* ent = (uint*)((char*)d_ws + xhB);
        const int nvec = n * CIN / 8;
        cvt_f16<<<(nvec + 255) / 256, 256, 0, stream>>>(x, xh, nvec);
        bucket_kernel<<<nwavesPad, 64, 0, stream>>>(aprs, lvl, ent, n);
        compute_kernel<<<nblocks, BWAV * 64, 0, stream>>>(xh, W, ent, out, n);
    } else if (ws_size >= xhB) {
        uint* xh = (uint*)d_ws;
        const int nvec = n * CIN / 8;
        cvt_bf16<<<(nvec + 255) / 256, 256, 0, stream>>>(x, xh, nvec);
        outblock_bf16<<<(n + 255) / 256, 256, 0, stream>>>(xh, W, aprs, lvl, out, n);
    } else {
        outblock_f32<<<(n + 255) / 256, 256, 0, stream>>>(x, W, aprs, lvl, out, n);
    }
}